// Round 1
// baseline (33.346 us; speedup 1.0000x reference)
//
#include <hip/hip_runtime.h>

// Problem: out[b,h] = (X X^T) X  ==  X (X^T X)  per head, X = x[b,h] : [2048 x 64], fp32.
// B*H = 32 heads. Reassociation: G = X^T X (64x64), out = X G.

#define TDIM 2048
#define DDIM 64
#define NHEADS 32

// ---------------------------------------------------------------------------
// Kernel 1: partial Gram matrices.
// grid = (nchunks, NHEADS), block = 256.
// part[head][chunk][i][j] = sum over this chunk's rows t of x[t][i]*x[t][j].
// Each thread owns a 4x4 tile of G: i0=(tid>>4)*4, j0=(tid&15)*4.
// LDS x-stage padded to 68 floats/row -> all inner reads <=2-way bank aliasing.
// ---------------------------------------------------------------------------
__global__ __launch_bounds__(256) void gram_partial(const float* __restrict__ x,
                                                    float* __restrict__ part,
                                                    int rows_per_chunk) {
    const int head  = blockIdx.y;
    const int chunk = blockIdx.x;
    const int nch   = gridDim.x;
    const int tid   = threadIdx.x;

    const float* xh = x + ((size_t)head * TDIM + (size_t)chunk * rows_per_chunk) * DDIM;

    __shared__ float xs[64][68];

    const int i0 = (tid >> 4) << 2;
    const int j0 = (tid & 15) << 2;

    float acc[4][4];
#pragma unroll
    for (int a = 0; a < 4; ++a)
#pragma unroll
        for (int b = 0; b < 4; ++b) acc[a][b] = 0.f;

    for (int base = 0; base < rows_per_chunk; base += 64) {
        __syncthreads();  // protect xs against waves still reading previous stage
#pragma unroll
        for (int l = 0; l < 4; ++l) {
            const int f = l * 256 + tid;   // float4 index within 64x64 stage
            const int r = f >> 4;
            const int c = (f & 15) << 2;
            *reinterpret_cast<float4*>(&xs[r][c]) =
                *reinterpret_cast<const float4*>(xh + (size_t)(base + r) * DDIM + c);
        }
        __syncthreads();
#pragma unroll 4
        for (int t = 0; t < 64; ++t) {
            const float4 av = *reinterpret_cast<const float4*>(&xs[t][i0]);
            const float4 bv = *reinterpret_cast<const float4*>(&xs[t][j0]);
            const float aa[4] = {av.x, av.y, av.z, av.w};
            const float bb[4] = {bv.x, bv.y, bv.z, bv.w};
#pragma unroll
            for (int a = 0; a < 4; ++a)
#pragma unroll
                for (int b = 0; b < 4; ++b) acc[a][b] += aa[a] * bb[b];
        }
    }

    float* p = part + ((size_t)head * nch + chunk) * 4096;
#pragma unroll
    for (int a = 0; a < 4; ++a)
        *reinterpret_cast<float4*>(p + (i0 + a) * 64 + j0) =
            make_float4(acc[a][0], acc[a][1], acc[a][2], acc[a][3]);
}

// ---------------------------------------------------------------------------
// Kernel 2: deterministic fixed-order reduction of partials -> G[32][64][64].
// grid = 512 blocks x 256 threads = 131072 threads, one per G element.
// ---------------------------------------------------------------------------
__global__ __launch_bounds__(256) void gram_reduce(const float* __restrict__ part,
                                                   float* __restrict__ G, int nch) {
    const int gid = blockIdx.x * 256 + threadIdx.x;  // 0 .. 32*4096-1
    const int h = gid >> 12;
    const int e = gid & 4095;
    float s = 0.f;
    for (int c = 0; c < nch; ++c) s += part[((size_t)h * nch + c) * 4096 + e];
    G[gid] = s;
}

// ---------------------------------------------------------------------------
// Kernel 3: out = X * G.  grid = (TDIM/64, NHEADS), block = 256.
// G (16 KB) + 64-row x stage (padded) in LDS. Each thread: 4 rows x 4 cols.
// ---------------------------------------------------------------------------
__global__ __launch_bounds__(256) void xg_kernel(const float* __restrict__ x,
                                                 const float* __restrict__ G,
                                                 float* __restrict__ out) {
    const int head = blockIdx.y;
    const int row0 = blockIdx.x * 64;
    const int tid  = threadIdx.x;

    __shared__ float Gs[64 * 64];
    __shared__ float xs[64][68];

    const float* xh = x + ((size_t)head * TDIM + row0) * DDIM;
    const float* Gh = G + (size_t)head * 4096;

#pragma unroll
    for (int k = 0; k < 16; ++k) Gs[k * 256 + tid] = Gh[k * 256 + tid];

#pragma unroll
    for (int l = 0; l < 4; ++l) {
        const int f = l * 256 + tid;
        const int r = f >> 4;
        const int c = (f & 15) << 2;
        *reinterpret_cast<float4*>(&xs[r][c]) =
            *reinterpret_cast<const float4*>(xh + (size_t)r * DDIM + c);
    }
    __syncthreads();

    const int r0 = (tid >> 4) << 2;
    const int d0 = (tid & 15) << 2;

    float acc[4][4];
#pragma unroll
    for (int a = 0; a < 4; ++a)
#pragma unroll
        for (int b = 0; b < 4; ++b) acc[a][b] = 0.f;

#pragma unroll 4
    for (int i = 0; i < 64; i += 4) {
        float4 g[4];
        float4 xv[4];
#pragma unroll
        for (int ii = 0; ii < 4; ++ii)
            g[ii] = *reinterpret_cast<const float4*>(&Gs[(i + ii) * 64 + d0]);
#pragma unroll
        for (int k = 0; k < 4; ++k)
            xv[k] = *reinterpret_cast<const float4*>(&xs[r0 + k][i]);
#pragma unroll
        for (int k = 0; k < 4; ++k) {
            const float xk[4] = {xv[k].x, xv[k].y, xv[k].z, xv[k].w};
#pragma unroll
            for (int ii = 0; ii < 4; ++ii) {
                acc[k][0] += xk[ii] * g[ii].x;
                acc[k][1] += xk[ii] * g[ii].y;
                acc[k][2] += xk[ii] * g[ii].z;
                acc[k][3] += xk[ii] * g[ii].w;
            }
        }
    }

    float* oh = out + ((size_t)head * TDIM + row0) * DDIM;
#pragma unroll
    for (int k = 0; k < 4; ++k)
        *reinterpret_cast<float4*>(oh + (size_t)(r0 + k) * DDIM + d0) =
            make_float4(acc[k][0], acc[k][1], acc[k][2], acc[k][3]);
}

extern "C" void kernel_launch(void* const* d_in, const int* in_sizes, int n_in,
                              void* d_out, int out_size, void* d_ws, size_t ws_size,
                              hipStream_t stream) {
    const float* x = (const float*)d_in[0];
    float* out = (float*)d_out;
    float* ws  = (float*)d_ws;

    // ws layout: [ part: NHEADS * nch * 4096 ][ G: NHEADS * 4096 ] floats.
    int nch = 16;
    while (nch > 1 &&
           ws_size < (size_t)(nch + 1) * NHEADS * 4096 * sizeof(float))
        nch >>= 1;

    float* part = ws;
    float* G    = ws + (size_t)NHEADS * nch * 4096;
    const int rows_per_chunk = TDIM / nch;

    dim3 g1(nch, NHEADS);
    gram_partial<<<g1, 256, 0, stream>>>(x, part, rows_per_chunk);

    gram_reduce<<<(NHEADS * 4096) / 256, 256, 0, stream>>>(part, G, nch);

    dim3 g2(TDIM / 64, NHEADS);
    xg_kernel<<<g2, 256, 0, stream>>>(x, G, out);
}